// Round 7
// baseline (293.545 us; speedup 1.0000x reference)
//
#include <hip/hip_runtime.h>

typedef unsigned long long u64;
typedef unsigned short u16;
typedef __bf16 bf16_t;
typedef bf16_t bf16x8 __attribute__((ext_vector_type(8)));
typedef float f32x4 __attribute__((ext_vector_type(4)));

#define NN 4096
#define NH 3
#define NPAIR 131072
#define LOG2E 1.4426950408889634f

union U8 { uint4 u; bf16x8 b; };

__device__ __forceinline__ u16 f2us(float f) {
  unsigned int x = __float_as_uint(f);
  x = x + 0x7fffu + ((x >> 16) & 1u);
  return (u16)(x >> 16);
}
__device__ __forceinline__ unsigned int pk2(float a, float b) {
  return (unsigned int)f2us(a) | ((unsigned int)f2us(b) << 16);
}
__device__ __forceinline__ float geluf(float x) {
  return 0.5f * x * (1.f + erff(x * 0.70710678118654752f));
}
__device__ __forceinline__ float exp2fast(float x) {
#if __has_builtin(__builtin_amdgcn_exp2f)
  return __builtin_amdgcn_exp2f(x);
#else
  return __expf(x * 0.6931471805599453f);
#endif
}

// ---- adj int32 [N][N] -> bitmask u64 [N][N/64] ----
__global__ __launch_bounds__(256) void k_bitmask(const int* __restrict__ adj,
                                                 u64* __restrict__ bm) {
  int i = blockIdx.x;
  int lane = threadIdx.x & 63;
  int wv = threadIdx.x >> 6;
  const int* row = adj + (size_t)i * NN;
  for (int wq = wv; wq < NN / 64; wq += 4) {
    u64 b = __ballot(row[wq * 64 + lane] > 0);
    if (lane == 0) bm[(size_t)i * (NN / 64) + wq] = b;
  }
}

// ---- bf16 tables: emb16[4096][256], WT1[h][128][256], WT2[h][128][384],
//      linWT[128][384] ----
__global__ __launch_bounds__(256) void k_prep(
    const float* __restrict__ emb, const float* __restrict__ W1,
    const float* __restrict__ W2, const float* __restrict__ linW,
    u16* __restrict__ emb16, u16* __restrict__ WT1, u16* __restrict__ WT2,
    u16* __restrict__ linWT) {
  int idx = blockIdx.x * 256 + threadIdx.x;
  if (idx < 1048576) { emb16[idx] = f2us(emb[idx]); return; }
  idx -= 1048576;
  if (idx < 98304) {
    int h = idx / 32768, r = idx & 32767, f = r >> 8, k = r & 255;
    WT1[idx] = f2us(W1[h * 32768 + k * 128 + f]);
    return;
  }
  idx -= 98304;
  if (idx < 147456) {
    int h = idx / 49152, r = idx % 49152, f = r / 384, k = r % 384;
    WT2[idx] = f2us(W2[h * 49152 + k * 128 + f]);
    return;
  }
  idx -= 147456;
  if (idx < 49152) {
    int f = idx / 384, k = idx % 384;
    linWT[idx] = f2us(linW[k * 128 + f]);
  }
}

// ---- Wh = x @ W via MFMA, 1 wave / 16 rows, B single-buffered in regs ----
template <int K>
__global__ __launch_bounds__(64, 4) void k_wh(const u16* __restrict__ xb,
                                              const u16* __restrict__ WT,
                                              const float* __restrict__ av,
                                              u16* __restrict__ WhT,
                                              float* __restrict__ s1,
                                              float* __restrict__ s2) {
  constexpr int NS = K / 32;
  int h = blockIdx.y, l = threadIdx.x, li = l & 15, lg = l >> 4;
  int iw = blockIdx.x * 16;
  const u16* Wb = WT + (size_t)h * 128 * K;
  const u16* xr = xb + (size_t)(iw + li) * K;

  f32x4 acc[8];
#pragma unroll
  for (int nt = 0; nt < 8; ++nt) acc[nt] = (f32x4){0.f, 0.f, 0.f, 0.f};

#pragma unroll 2
  for (int s = 0; s < NS; ++s) {
    int j0 = s * 32 + lg * 8;
    uint4 xa = *(const uint4*)(xr + j0);
    uint4 b[8];
#pragma unroll
    for (int nt = 0; nt < 8; ++nt)
      b[nt] = *(const uint4*)(Wb + (size_t)(nt * 16 + li) * K + j0);
    U8 af;
    af.u = xa;
#pragma unroll
    for (int nt = 0; nt < 8; ++nt) {
      U8 bb;
      bb.u = b[nt];
      acc[nt] = __builtin_amdgcn_mfma_f32_16x16x32_bf16(af.b, bb.b, acc[nt], 0, 0, 0);
    }
  }

  float p1[4] = {0.f, 0.f, 0.f, 0.f}, p2[4] = {0.f, 0.f, 0.f, 0.f};
#pragma unroll
  for (int nt = 0; nt < 8; ++nt) {
    float a1 = av[h * 256 + nt * 16 + li];
    float a2 = av[h * 256 + 128 + nt * 16 + li];
#pragma unroll
    for (int r = 0; r < 4; ++r) {
      p1[r] = fmaf(acc[nt][r], a1, p1[r]);
      p2[r] = fmaf(acc[nt][r], a2, p2[r]);
    }
  }
#pragma unroll
  for (int r = 0; r < 4; ++r) {
#pragma unroll
    for (int o = 1; o < 16; o <<= 1) {
      p1[r] += __shfl_xor(p1[r], o);
      p2[r] += __shfl_xor(p2[r], o);
    }
  }
  if (li == 0) {
#pragma unroll
    for (int r = 0; r < 4; ++r) {
      s1[h * NN + iw + lg * 4 + r] = p1[r] * LOG2E;
      s2[h * NN + iw + lg * 4 + r] = p2[r] * LOG2E;
    }
  }
  u16* WhTo = WhT + (size_t)h * 128 * NN;
#pragma unroll
  for (int nt = 0; nt < 8; ++nt) {
    uint2 pw;
    pw.x = pk2(acc[nt][0], acc[nt][1]);
    pw.y = pk2(acc[nt][2], acc[nt][3]);
    *(uint2*)(WhTo + (size_t)(nt * 16 + li) * NN + iw + lg * 4) = pw;
  }
}

// ---- attention accumulate: block = M=32 x (2 N-halves x 4 K-chunks) waves.
//      B single-buffered; s2/masks issued first so vmcnt overlaps p-VALU with
//      B latency; dn via ones-MFMA ----
__global__ __launch_bounds__(512, 4) void k_acc(
    const u64* __restrict__ bm, const u16* __restrict__ WhT,
    const float* __restrict__ s1, const float* __restrict__ s2,
    const float* __restrict__ at1f_in, const float* __restrict__ amix,
    const float* __restrict__ bmix, float* __restrict__ at1f_out,
    u16* __restrict__ at1b_out, u16* __restrict__ att_out, int mode) {
  int h = blockIdx.y, t = threadIdx.x, w = t >> 6, l = t & 63;
  int li = l & 15, lg = l >> 4;
  int nh = w & 1, kc = w >> 1;
  int i0 = blockIdx.x * 32;
  int k0w = kc * 1024;
  const u16* Wb = WhT + (size_t)h * 128 * NN;
  const float* s2h = s2 + h * NN;
  float s1i0 = s1[h * NN + i0 + li];
  float s1i1 = s1[h * NN + i0 + 16 + li];
  const unsigned char* bmr0 = (const unsigned char*)bm + (size_t)(i0 + li) * 512;
  const unsigned char* bmr1 = bmr0 + 16 * 512;

  const u16* brow[4];
#pragma unroll
  for (int nt = 0; nt < 4; ++nt)
    brow[nt] = Wb + (size_t)(nh * 64 + nt * 16 + li) * NN + lg * 8;

  f32x4 acc[2][4];
  f32x4 accD[2];
#pragma unroll
  for (int m = 0; m < 2; ++m) {
    accD[m] = (f32x4){0.f, 0.f, 0.f, 0.f};
#pragma unroll
    for (int nt = 0; nt < 4; ++nt) acc[m][nt] = (f32x4){0.f, 0.f, 0.f, 0.f};
  }
  U8 ones;
  ones.u = make_uint4(0x3F803F80u, 0x3F803F80u, 0x3F803F80u, 0x3F803F80u);

#pragma unroll 2
  for (int s = 0; s < 32; ++s) {
    int j0 = k0w + s * 32;
    // small loads FIRST (older in vmcnt queue -> p-compute waits only these)
    float4 s2a = *(const float4*)(s2h + j0 + lg * 8);
    float4 s2b = *(const float4*)(s2h + j0 + lg * 8 + 4);
    unsigned int mb0 = bmr0[(j0 >> 3) + lg];
    unsigned int mb1 = bmr1[(j0 >> 3) + lg];
    // B loads (newer) stay in flight during p-compute
    uint4 b0 = *(const uint4*)(brow[0] + j0);
    uint4 b1 = *(const uint4*)(brow[1] + j0);
    uint4 b2 = *(const uint4*)(brow[2] + j0);
    uint4 b3 = *(const uint4*)(brow[3] + j0);
    float se[8] = {s2a.x, s2a.y, s2a.z, s2a.w, s2b.x, s2b.y, s2b.z, s2b.w};
    U8 a0, a1;
#pragma unroll
    for (int e = 0; e < 8; ++e) {
      float t0 = s1i0 + se[e];
      t0 = fmaxf(t0, 0.2f * t0);
      t0 = ((mb0 >> e) & 1u) ? t0 : -1e30f;
      a0.b[e] = (bf16_t)exp2fast(t0);
      float t1 = s1i1 + se[e];
      t1 = fmaxf(t1, 0.2f * t1);
      t1 = ((mb1 >> e) & 1u) ? t1 : -1e30f;
      a1.b[e] = (bf16_t)exp2fast(t1);
    }
    U8 B0, B1, B2, B3;
    B0.u = b0; B1.u = b1; B2.u = b2; B3.u = b3;
    acc[0][0] = __builtin_amdgcn_mfma_f32_16x16x32_bf16(a0.b, B0.b, acc[0][0], 0, 0, 0);
    acc[1][0] = __builtin_amdgcn_mfma_f32_16x16x32_bf16(a1.b, B0.b, acc[1][0], 0, 0, 0);
    acc[0][1] = __builtin_amdgcn_mfma_f32_16x16x32_bf16(a0.b, B1.b, acc[0][1], 0, 0, 0);
    acc[1][1] = __builtin_amdgcn_mfma_f32_16x16x32_bf16(a1.b, B1.b, acc[1][1], 0, 0, 0);
    acc[0][2] = __builtin_amdgcn_mfma_f32_16x16x32_bf16(a0.b, B2.b, acc[0][2], 0, 0, 0);
    acc[1][2] = __builtin_amdgcn_mfma_f32_16x16x32_bf16(a1.b, B2.b, acc[1][2], 0, 0, 0);
    acc[0][3] = __builtin_amdgcn_mfma_f32_16x16x32_bf16(a0.b, B3.b, acc[0][3], 0, 0, 0);
    acc[1][3] = __builtin_amdgcn_mfma_f32_16x16x32_bf16(a1.b, B3.b, acc[1][3], 0, 0, 0);
    accD[0] = __builtin_amdgcn_mfma_f32_16x16x32_bf16(a0.b, ones.b, accD[0], 0, 0, 0);
    accD[1] = __builtin_amdgcn_mfma_f32_16x16x32_bf16(a1.b, ones.b, accD[1], 0, 0, 0);
  }

  // cross-wave reduce: 4 K-chunk phases; N-halves write disjoint cols
  __shared__ float red[32][132];
  __shared__ float dnred[32];
  for (int ph = 0; ph < 4; ++ph) {
    if (kc == ph) {
#pragma unroll
      for (int m = 0; m < 2; ++m)
#pragma unroll
        for (int nt = 0; nt < 4; ++nt)
#pragma unroll
          for (int r = 0; r < 4; ++r) {
            int row = m * 16 + lg * 4 + r, col = nh * 64 + nt * 16 + li;
            float v = acc[m][nt][r];
            if (ph == 0) red[row][col] = v;
            else red[row][col] += v;
          }
      if (nh == 0 && li == 0) {
#pragma unroll
        for (int m = 0; m < 2; ++m)
#pragma unroll
          for (int r = 0; r < 4; ++r) {
            int row = m * 16 + lg * 4 + r;
            float v = accD[m][r];
            if (ph == 0) dnred[row] = v;
            else dnred[row] += v;
          }
      }
    }
    __syncthreads();
  }

  float wa = 1.f, wb = 0.f;
  if (mode) {
    float A = amix[0], B = bmix[0];
    wa = A / (A + B);
    wb = B / (A + B);
  }
#pragma unroll 1
  for (int q = t; q < 32 * 128; q += 512) {
    int row = q >> 7, col = q & 127;
    float inv = 1.f / fmaxf(dnred[row], 1e-30f);
    float v = red[row][col] * inv;
    v = v > 0.f ? v : (exp2fast(v * LOG2E) - 1.f);
    size_t oi = (size_t)(i0 + row) * 384 + h * 128 + col;
    if (mode == 0) {
      at1f_out[oi] = v;
      at1b_out[oi] = f2us(v);
    } else {
      att_out[oi] = f2us(wa * at1f_in[oi] + wb * v);
    }
  }
}

// ---- pair scoring: 8 waves x 32 pairs, linWT in LDS, B read inline from LDS,
//      only the 4 gather uint4s double-buffered ----
__global__ __launch_bounds__(512, 2) void k_pairs(
    const int* __restrict__ aidx, const int* __restrict__ bidx,
    const u16* __restrict__ attB, const u16* __restrict__ linWT,
    const float* __restrict__ linB, const float* __restrict__ outW,
    const float* __restrict__ outB, const float* __restrict__ embB,
    float* __restrict__ out) {
  __shared__ __align__(16) u16 Wlds[128][392];  // ~100KB
  int t = threadIdx.x, w = t >> 6, l = t & 63;
  int li = l & 15, lg = l >> 4;
  {  // one-time stage
    int r = t >> 2, seg = (t & 3) * 96;
    const u16* src = linWT + (size_t)r * 384 + seg;
    u16* dst = &Wlds[r][seg];
#pragma unroll
    for (int q = 0; q < 12; ++q)
      *(uint4*)(dst + q * 8) = *(const uint4*)(src + q * 8);
  }
  __syncthreads();

  int p0 = blockIdx.x * 256 + w * 32;
  int ia0 = aidx[p0 + li], ib0 = bidx[p0 + li];
  int ia1 = aidx[p0 + 16 + li], ib1 = bidx[p0 + 16 + li];
  const u16* ra0 = attB + (size_t)ia0 * 384;
  const u16* rb0 = attB + (size_t)ib0 * 384;
  const u16* ra1 = attB + (size_t)ia1 * 384;
  const u16* rb1 = attB + (size_t)ib1 * 384;

  f32x4 acc[2][8];
#pragma unroll
  for (int g = 0; g < 2; ++g)
#pragma unroll
    for (int nt = 0; nt < 8; ++nt) acc[g][nt] = (f32x4){0.f, 0.f, 0.f, 0.f};

#define LDG(UA, UB, UC, UD, S)                  \
  do {                                          \
    int j0_ = (S) * 32 + lg * 8;                \
    UA = *(const uint4*)(ra0 + j0_);            \
    UB = *(const uint4*)(rb0 + j0_);            \
    UC = *(const uint4*)(ra1 + j0_);            \
    UD = *(const uint4*)(rb1 + j0_);            \
  } while (0)
#define WORK(UA, UB, UC, UD, S)                                              \
  do {                                                                       \
    int j0_ = (S) * 32 + lg * 8;                                             \
    U8 xa_, xb_, af0_, af1_;                                                 \
    xa_.u = UA; xb_.u = UB;                                                  \
    _Pragma("unroll") for (int e = 0; e < 8; ++e)                            \
        af0_.b[e] = (bf16_t)((float)xa_.b[e] * (float)xb_.b[e]);             \
    xa_.u = UC; xb_.u = UD;                                                  \
    _Pragma("unroll") for (int e = 0; e < 8; ++e)                            \
        af1_.b[e] = (bf16_t)((float)xa_.b[e] * (float)xb_.b[e]);             \
    _Pragma("unroll") for (int nt = 0; nt < 8; ++nt) {                       \
      U8 bb_;                                                                \
      bb_.u = *(const uint4*)&Wlds[nt * 16 + li][j0_];                       \
      acc[0][nt] = __builtin_amdgcn_mfma_f32_16x16x32_bf16(af0_.b, bb_.b,    \
                                                  acc[0][nt], 0, 0, 0);      \
      acc[1][nt] = __builtin_amdgcn_mfma_f32_16x16x32_bf16(af1_.b, bb_.b,    \
                                                  acc[1][nt], 0, 0, 0);      \
    }                                                                        \
  } while (0)

  uint4 uaA, ubA, ucA, udA, uaB, ubB, ucB, udB;
  LDG(uaA, ubA, ucA, udA, 0);
  for (int s = 0; s < 12; s += 2) {
    LDG(uaB, ubB, ucB, udB, s + 1);
    WORK(uaA, ubA, ucA, udA, s);
    if (s + 2 < 12) LDG(uaA, ubA, ucA, udA, s + 2);
    WORK(uaB, ubB, ucB, udB, s + 1);
  }
#undef LDG
#undef WORK

#pragma unroll
  for (int g = 0; g < 2; ++g) {
    float z[4] = {0.f, 0.f, 0.f, 0.f};
#pragma unroll
    for (int nt = 0; nt < 8; ++nt) {
      int f = nt * 16 + li;
      float lb = linB[f], ow = outW[f];
#pragma unroll
      for (int r = 0; r < 4; ++r) {
        float y = geluf(acc[g][nt][r] + lb);
        z[r] = fmaf(y, ow, z[r]);
      }
    }
#pragma unroll
    for (int r = 0; r < 4; ++r) {
      z[r] += __shfl_xor(z[r], 1);
      z[r] += __shfl_xor(z[r], 2);
      z[r] += __shfl_xor(z[r], 4);
      z[r] += __shfl_xor(z[r], 8);
    }
    if (li == 0) {
#pragma unroll
      for (int r = 0; r < 4; ++r) {
        int pi = p0 + g * 16 + lg * 4 + r;
        float badd = geluf(embB[aidx[pi]] + embB[bidx[pi]]);
        float zz = z[r] + badd * outW[128] + outB[0];
        out[pi] = 1.f / (1.f + __expf(-zz));
      }
    }
  }
}

extern "C" void kernel_launch(void* const* d_in, const int* in_sizes, int n_in,
                              void* d_out, int out_size, void* d_ws, size_t ws_size,
                              hipStream_t stream) {
  (void)in_sizes; (void)n_in; (void)out_size; (void)ws_size;
  const int* aidx = (const int*)d_in[0];
  const int* bidx = (const int*)d_in[1];
  const int* adj = (const int*)d_in[2];
  const float* emb = (const float*)d_in[3];
  const float* embB = (const float*)d_in[4];
  const float* W1 = (const float*)d_in[5];
  const float* av1 = (const float*)d_in[6];
  const float* W2 = (const float*)d_in[7];
  const float* av2 = (const float*)d_in[8];
  const float* amix = (const float*)d_in[9];
  const float* bmix = (const float*)d_in[10];
  const float* linW = (const float*)d_in[11];
  const float* linB = (const float*)d_in[12];
  const float* outW = (const float*)d_in[13];
  const float* outB = (const float*)d_in[14];

  char* ws = (char*)d_ws;
  u64* bm = (u64*)(ws + 0);                         // 2MB
  u16* WhT = (u16*)(ws + (2u << 20));               // 3MB
  float* s1 = (float*)(ws + (5u << 20));            // 48KB
  float* s2 = (float*)(ws + (5u << 20) + (64u << 10));
  u16* linWT = (u16*)(ws + (5u << 20) + (128u << 10));  // 96KB
  u16* WT1 = (u16*)(ws + (5u << 20) + (256u << 10));    // 192KB
  u16* WT2 = (u16*)(ws + (5u << 20) + (512u << 10));    // 288KB
  float* at1f = (float*)(ws + (6u << 20));          // 6MB
  u16* sh12 = (u16*)(ws + (12u << 20));             // 3MB: emb16 -> at1b -> attB
  u16* emb16 = sh12;
  u16* at1b = sh12;
  u16* attB = sh12;

  k_bitmask<<<NN, 256, 0, stream>>>(adj, bm);
  k_prep<<<5248, 256, 0, stream>>>(emb, W1, W2, linW, emb16, WT1, WT2, linWT);
  k_wh<256><<<dim3(256, NH), 64, 0, stream>>>(emb16, WT1, av1, WhT, s1, s2);
  k_acc<<<dim3(128, NH), 512, 0, stream>>>(bm, WhT, s1, s2, at1f, amix, bmix,
                                           at1f, at1b, attB, 0);
  k_wh<384><<<dim3(256, NH), 64, 0, stream>>>(at1b, WT2, av2, WhT, s1, s2);
  k_acc<<<dim3(128, NH), 512, 0, stream>>>(bm, WhT, s1, s2, at1f, amix, bmix,
                                           at1f, at1b, attB, 1);
  k_pairs<<<NPAIR / 256, 512, 0, stream>>>(aidx, bidx, attB, linWT, linB, outW,
                                           outB, embB, (float*)d_out);
}

// Round 8
// 205.263 us; speedup vs baseline: 1.4301x; 1.4301x over previous
//
#include <hip/hip_runtime.h>

typedef unsigned long long u64;
typedef unsigned short u16;
typedef __bf16 bf16_t;
typedef bf16_t bf16x8 __attribute__((ext_vector_type(8)));
typedef float f32x4 __attribute__((ext_vector_type(4)));

#define NN 4096
#define NH 3
#define NPAIR 131072
#define LOG2E 1.4426950408889634f

union U8 { uint4 u; bf16x8 b; };

__device__ __forceinline__ u16 f2us(float f) {
  unsigned int x = __float_as_uint(f);
  x = x + 0x7fffu + ((x >> 16) & 1u);
  return (u16)(x >> 16);
}
__device__ __forceinline__ unsigned int pk2(float a, float b) {
  return (unsigned int)f2us(a) | ((unsigned int)f2us(b) << 16);
}
__device__ __forceinline__ float geluf(float x) {
  return 0.5f * x * (1.f + erff(x * 0.70710678118654752f));
}
__device__ __forceinline__ float exp2fast(float x) {
#if __has_builtin(__builtin_amdgcn_exp2f)
  return __builtin_amdgcn_exp2f(x);
#else
  return __expf(x * 0.6931471805599453f);
#endif
}

// ---- adj int32 [N][N] -> bitmask u64 [N][N/64] ----
__global__ __launch_bounds__(256) void k_bitmask(const int* __restrict__ adj,
                                                 u64* __restrict__ bm) {
  int i = blockIdx.x;
  int lane = threadIdx.x & 63;
  int wv = threadIdx.x >> 6;
  const int* row = adj + (size_t)i * NN;
  for (int wq = wv; wq < NN / 64; wq += 4) {
    u64 b = __ballot(row[wq * 64 + lane] > 0);
    if (lane == 0) bm[(size_t)i * (NN / 64) + wq] = b;
  }
}

// ---- fragment-major mask: bmF[ib(64)][jc(128)][lane(64)] u32 = 4 m-bytes ----
__global__ __launch_bounds__(256) void k_maskf(const u64* __restrict__ bm,
                                               unsigned int* __restrict__ bmF) {
  int idx = blockIdx.x * 256 + threadIdx.x;  // 524288 total
  int l = idx & 63, jc = (idx >> 6) & 127, ib = idx >> 13;
  int li = l & 15, lg = l >> 4;
  const unsigned char* b8 = (const unsigned char*)bm;
  unsigned int v = 0;
#pragma unroll
  for (int m = 0; m < 4; ++m)
    v |= (unsigned int)b8[(size_t)(ib * 64 + m * 16 + li) * 512 + jc * 4 + lg]
         << (8 * m);
  bmF[idx] = v;
}

// ---- bf16 tables: emb16[4096][256], WT1[h][128][256], WT2[h][128][384],
//      linWT[128][384] ----
__global__ __launch_bounds__(256) void k_prep(
    const float* __restrict__ emb, const float* __restrict__ W1,
    const float* __restrict__ W2, const float* __restrict__ linW,
    u16* __restrict__ emb16, u16* __restrict__ WT1, u16* __restrict__ WT2,
    u16* __restrict__ linWT) {
  int idx = blockIdx.x * 256 + threadIdx.x;
  if (idx < 1048576) { emb16[idx] = f2us(emb[idx]); return; }
  idx -= 1048576;
  if (idx < 98304) {
    int h = idx / 32768, r = idx & 32767, f = r >> 8, k = r & 255;
    WT1[idx] = f2us(W1[h * 32768 + k * 128 + f]);
    return;
  }
  idx -= 98304;
  if (idx < 147456) {
    int h = idx / 49152, r = idx % 49152, f = r / 384, k = r % 384;
    WT2[idx] = f2us(W2[h * 49152 + k * 128 + f]);
    return;
  }
  idx -= 147456;
  if (idx < 49152) {
    int f = idx / 384, k = idx % 384;
    linWT[idx] = f2us(linW[k * 128 + f]);
  }
}

// ---- Wh = x @ W via MFMA, 1 wave / 16 rows; writes fragment-major WhTF
//      [h][nt(8)][jc(128)][li(16)][lg(4)][e(8)] + E1/F1/E2/F2 exp tables ----
template <int K>
__global__ __launch_bounds__(64, 4) void k_wh(const u16* __restrict__ xb,
                                              const u16* __restrict__ WT,
                                              const float* __restrict__ av,
                                              u16* __restrict__ WhTF,
                                              float* __restrict__ E1,
                                              float* __restrict__ F1,
                                              float* __restrict__ E2,
                                              float* __restrict__ F2) {
  constexpr int NS = K / 32;
  int h = blockIdx.y, l = threadIdx.x, li = l & 15, lg = l >> 4;
  int iw = blockIdx.x * 16;
  const u16* Wb = WT + (size_t)h * 128 * K;
  const u16* xr = xb + (size_t)(iw + li) * K;

  f32x4 acc[8];
#pragma unroll
  for (int nt = 0; nt < 8; ++nt) acc[nt] = (f32x4){0.f, 0.f, 0.f, 0.f};

#pragma unroll 2
  for (int s = 0; s < NS; ++s) {
    int j0 = s * 32 + lg * 8;
    uint4 xa = *(const uint4*)(xr + j0);
    uint4 b[8];
#pragma unroll
    for (int nt = 0; nt < 8; ++nt)
      b[nt] = *(const uint4*)(Wb + (size_t)(nt * 16 + li) * K + j0);
    U8 af;
    af.u = xa;
#pragma unroll
    for (int nt = 0; nt < 8; ++nt) {
      U8 bb;
      bb.u = b[nt];
      acc[nt] = __builtin_amdgcn_mfma_f32_16x16x32_bf16(af.b, bb.b, acc[nt], 0, 0, 0);
    }
  }

  float p1[4] = {0.f, 0.f, 0.f, 0.f}, p2[4] = {0.f, 0.f, 0.f, 0.f};
#pragma unroll
  for (int nt = 0; nt < 8; ++nt) {
    float a1 = av[h * 256 + nt * 16 + li];
    float a2 = av[h * 256 + 128 + nt * 16 + li];
#pragma unroll
    for (int r = 0; r < 4; ++r) {
      p1[r] = fmaf(acc[nt][r], a1, p1[r]);
      p2[r] = fmaf(acc[nt][r], a2, p2[r]);
    }
  }
#pragma unroll
  for (int r = 0; r < 4; ++r) {
#pragma unroll
    for (int o = 1; o < 16; o <<= 1) {
      p1[r] += __shfl_xor(p1[r], o);
      p2[r] += __shfl_xor(p2[r], o);
    }
  }
  if (li == 0) {
#pragma unroll
    for (int r = 0; r < 4; ++r) {
      int idx = h * NN + iw + lg * 4 + r;
      float s1L = p1[r] * LOG2E, s2L = p2[r] * LOG2E;
      E1[idx] = exp2fast(s1L);
      F1[idx] = exp2fast(0.2f * s1L);
      E2[idx] = exp2fast(s2L);
      F2[idx] = exp2fast(0.2f * s2L);
    }
  }
  // fragment-major write: f = nt*16+li -> (nt, row li); j = iw+lg*4+r
  u16* Wo = WhTF + (size_t)h * 524288;
  int jc = iw >> 5, jin = (iw & 31) + lg * 4;
#pragma unroll
  for (int nt = 0; nt < 8; ++nt) {
    uint2 pw;
    pw.x = pk2(acc[nt][0], acc[nt][1]);
    pw.y = pk2(acc[nt][2], acc[nt][3]);
    *(uint2*)(Wo + (size_t)nt * 65536 + (size_t)jc * 512 + li * 32 + jin) = pw;
  }
}

// ---- attention accumulate: M=64/block, grid 64x3 (<=1 block/CU), 8 waves =
//      (nh 2) x (kc 4); fragment-major B (1KB contiguous/load) + packed mask
//      u32/load; factorized P = max(E1*E2, F1*F2); dn via ones-MFMA ----
__global__ __launch_bounds__(512) void k_acc(
    const unsigned int* __restrict__ bmF, const u16* __restrict__ WhTF,
    const float* __restrict__ E1, const float* __restrict__ F1,
    const float* __restrict__ E2, const float* __restrict__ F2,
    const float* __restrict__ at1f_in, const float* __restrict__ amix,
    const float* __restrict__ bmix, float* __restrict__ at1f_out,
    u16* __restrict__ at1b_out, u16* __restrict__ att_out, int mode) {
  int h = blockIdx.y, t = threadIdx.x, w = t >> 6, l = t & 63;
  int li = l & 15, lg = l >> 4;
  int nh = w & 1, kc = w >> 1;
  int i0 = blockIdx.x * 64;
  int k0 = kc * 1024;
  const u16* Wb = WhTF + (size_t)h * 524288 + (size_t)(k0 >> 5) * 512 + li * 32 + lg * 8;
  const float* E2h = E2 + h * NN;
  const float* F2h = F2 + h * NN;
  float e1v[4], f1v[4];
#pragma unroll
  for (int m = 0; m < 4; ++m) {
    e1v[m] = E1[h * NN + i0 + m * 16 + li];
    f1v[m] = F1[h * NN + i0 + m * 16 + li];
  }
  const unsigned int* mrow =
      bmF + ((size_t)(i0 >> 6) * 128 + (k0 >> 5)) * 64 + l;
  const u16* bbase[4];
#pragma unroll
  for (int nt = 0; nt < 4; ++nt)
    bbase[nt] = Wb + (size_t)(nh * 4 + nt) * 65536;

  f32x4 acc[4][4];
  f32x4 accD[4];
#pragma unroll
  for (int m = 0; m < 4; ++m) {
    accD[m] = (f32x4){0.f, 0.f, 0.f, 0.f};
#pragma unroll
    for (int nt = 0; nt < 4; ++nt) acc[m][nt] = (f32x4){0.f, 0.f, 0.f, 0.f};
  }
  U8 ones;
  ones.u = make_uint4(0x3F803F80u, 0x3F803F80u, 0x3F803F80u, 0x3F803F80u);

#pragma unroll 2
  for (int s = 0; s < 32; ++s) {
    int j0 = k0 + s * 32;
    unsigned int mw = mrow[s * 64];
    float4 e2a = *(const float4*)(E2h + j0 + lg * 8);
    float4 e2b = *(const float4*)(E2h + j0 + lg * 8 + 4);
    float4 f2a = *(const float4*)(F2h + j0 + lg * 8);
    float4 f2b = *(const float4*)(F2h + j0 + lg * 8 + 4);
    uint4 b0 = *(const uint4*)(bbase[0] + s * 512);
    uint4 b1 = *(const uint4*)(bbase[1] + s * 512);
    uint4 b2 = *(const uint4*)(bbase[2] + s * 512);
    uint4 b3 = *(const uint4*)(bbase[3] + s * 512);
    float ea[8] = {e2a.x, e2a.y, e2a.z, e2a.w, e2b.x, e2b.y, e2b.z, e2b.w};
    float fa[8] = {f2a.x, f2a.y, f2a.z, f2a.w, f2b.x, f2b.y, f2b.z, f2b.w};
    U8 A[4];
#pragma unroll
    for (int m = 0; m < 4; ++m) {
      unsigned int mb = (mw >> (8 * m)) & 0xffu;
#pragma unroll
      for (int e = 0; e < 8; ++e) {
        float p = fmaxf(e1v[m] * ea[e], f1v[m] * fa[e]);
        A[m].b[e] = (bf16_t)(((mb >> e) & 1u) ? p : 0.f);
      }
    }
    U8 B0, B1, B2, B3;
    B0.u = b0; B1.u = b1; B2.u = b2; B3.u = b3;
#pragma unroll
    for (int m = 0; m < 4; ++m) {
      acc[m][0] = __builtin_amdgcn_mfma_f32_16x16x32_bf16(A[m].b, B0.b, acc[m][0], 0, 0, 0);
      acc[m][1] = __builtin_amdgcn_mfma_f32_16x16x32_bf16(A[m].b, B1.b, acc[m][1], 0, 0, 0);
      acc[m][2] = __builtin_amdgcn_mfma_f32_16x16x32_bf16(A[m].b, B2.b, acc[m][2], 0, 0, 0);
      acc[m][3] = __builtin_amdgcn_mfma_f32_16x16x32_bf16(A[m].b, B3.b, acc[m][3], 0, 0, 0);
      accD[m] = __builtin_amdgcn_mfma_f32_16x16x32_bf16(A[m].b, ones.b, accD[m], 0, 0, 0);
    }
  }

  // cross-wave reduce over kc; nh halves write disjoint columns
  __shared__ float red[64][132];
  __shared__ float dnred[64];
  for (int ph = 0; ph < 4; ++ph) {
    if (kc == ph) {
#pragma unroll
      for (int m = 0; m < 4; ++m)
#pragma unroll
        for (int nt = 0; nt < 4; ++nt)
#pragma unroll
          for (int r = 0; r < 4; ++r) {
            int row = m * 16 + lg * 4 + r, col = nh * 64 + nt * 16 + li;
            float v = acc[m][nt][r];
            if (ph == 0) red[row][col] = v;
            else red[row][col] += v;
          }
      if (nh == 0 && li == 0) {
#pragma unroll
        for (int m = 0; m < 4; ++m)
#pragma unroll
          for (int r = 0; r < 4; ++r) {
            int row = m * 16 + lg * 4 + r;
            float v = accD[m][r];
            if (ph == 0) dnred[row] = v;
            else dnred[row] += v;
          }
      }
    }
    __syncthreads();
  }

  float wa = 1.f, wb = 0.f;
  if (mode) {
    float Am = amix[0], Bm = bmix[0];
    wa = Am / (Am + Bm);
    wb = Bm / (Am + Bm);
  }
#pragma unroll 1
  for (int q = t; q < 64 * 128; q += 512) {
    int row = q >> 7, col = q & 127;
    float inv = 1.f / fmaxf(dnred[row], 1e-30f);
    float v = red[row][col] * inv;
    v = v > 0.f ? v : (exp2fast(v * LOG2E) - 1.f);
    size_t oi = (size_t)(i0 + row) * 384 + h * 128 + col;
    if (mode == 0) {
      at1f_out[oi] = v;
      at1b_out[oi] = f2us(v);
    } else {
      att_out[oi] = f2us(wa * at1f_in[oi] + wb * v);
    }
  }
}

// ---- pair scoring: 8 waves x 32 pairs, linWT in LDS, gathers double-buffered ----
__global__ __launch_bounds__(512) void k_pairs(
    const int* __restrict__ aidx, const int* __restrict__ bidx,
    const u16* __restrict__ attB, const u16* __restrict__ linWT,
    const float* __restrict__ linB, const float* __restrict__ outW,
    const float* __restrict__ outB, const float* __restrict__ embB,
    float* __restrict__ out) {
  __shared__ __align__(16) u16 Wlds[128][392];  // ~100KB
  int t = threadIdx.x, w = t >> 6, l = t & 63;
  int li = l & 15, lg = l >> 4;
  {  // one-time stage
    int r = t >> 2, seg = (t & 3) * 96;
    const u16* src = linWT + (size_t)r * 384 + seg;
    u16* dst = &Wlds[r][seg];
#pragma unroll
    for (int q = 0; q < 12; ++q)
      *(uint4*)(dst + q * 8) = *(const uint4*)(src + q * 8);
  }
  __syncthreads();

  int p0 = blockIdx.x * 256 + w * 32;
  int ia0 = aidx[p0 + li], ib0 = bidx[p0 + li];
  int ia1 = aidx[p0 + 16 + li], ib1 = bidx[p0 + 16 + li];
  const u16* ra0 = attB + (size_t)ia0 * 384;
  const u16* rb0 = attB + (size_t)ib0 * 384;
  const u16* ra1 = attB + (size_t)ia1 * 384;
  const u16* rb1 = attB + (size_t)ib1 * 384;

  f32x4 acc[2][8];
#pragma unroll
  for (int g = 0; g < 2; ++g)
#pragma unroll
    for (int nt = 0; nt < 8; ++nt) acc[g][nt] = (f32x4){0.f, 0.f, 0.f, 0.f};

#define LDG(UA, UB, UC, UD, S)                  \
  do {                                          \
    int j0_ = (S) * 32 + lg * 8;                \
    UA = *(const uint4*)(ra0 + j0_);            \
    UB = *(const uint4*)(rb0 + j0_);            \
    UC = *(const uint4*)(ra1 + j0_);            \
    UD = *(const uint4*)(rb1 + j0_);            \
  } while (0)
#define WORK(UA, UB, UC, UD, S)                                              \
  do {                                                                       \
    int j0_ = (S) * 32 + lg * 8;                                             \
    U8 xa_, xb_, af0_, af1_;                                                 \
    xa_.u = UA; xb_.u = UB;                                                  \
    _Pragma("unroll") for (int e = 0; e < 8; ++e)                            \
        af0_.b[e] = (bf16_t)((float)xa_.b[e] * (float)xb_.b[e]);             \
    xa_.u = UC; xb_.u = UD;                                                  \
    _Pragma("unroll") for (int e = 0; e < 8; ++e)                            \
        af1_.b[e] = (bf16_t)((float)xa_.b[e] * (float)xb_.b[e]);             \
    _Pragma("unroll") for (int nt = 0; nt < 8; ++nt) {                       \
      U8 bb_;                                                                \
      bb_.u = *(const uint4*)&Wlds[nt * 16 + li][j0_];                       \
      acc[0][nt] = __builtin_amdgcn_mfma_f32_16x16x32_bf16(af0_.b, bb_.b,    \
                                                  acc[0][nt], 0, 0, 0);      \
      acc[1][nt] = __builtin_amdgcn_mfma_f32_16x16x32_bf16(af1_.b, bb_.b,    \
                                                  acc[1][nt], 0, 0, 0);      \
    }                                                                        \
  } while (0)

  uint4 uaA, ubA, ucA, udA, uaB, ubB, ucB, udB;
  LDG(uaA, ubA, ucA, udA, 0);
  for (int s = 0; s < 12; s += 2) {
    LDG(uaB, ubB, ucB, udB, s + 1);
    WORK(uaA, ubA, ucA, udA, s);
    if (s + 2 < 12) LDG(uaA, ubA, ucA, udA, s + 2);
    WORK(uaB, ubB, ucB, udB, s + 1);
  }
#undef LDG
#undef WORK

#pragma unroll
  for (int g = 0; g < 2; ++g) {
    float z[4] = {0.f, 0.f, 0.f, 0.f};
#pragma unroll
    for (int nt = 0; nt < 8; ++nt) {
      int f = nt * 16 + li;
      float lb = linB[f], ow = outW[f];
#pragma unroll
      for (int r = 0; r < 4; ++r) {
        float y = geluf(acc[g][nt][r] + lb);
        z[r] = fmaf(y, ow, z[r]);
      }
    }
#pragma unroll
    for (int r = 0; r < 4; ++r) {
      z[r] += __shfl_xor(z[r], 1);
      z[r] += __shfl_xor(z[r], 2);
      z[r] += __shfl_xor(z[r], 4);
      z[r] += __shfl_xor(z[r], 8);
    }
    if (li == 0) {
#pragma unroll
      for (int r = 0; r < 4; ++r) {
        int pi = p0 + g * 16 + lg * 4 + r;
        float badd = geluf(embB[aidx[pi]] + embB[bidx[pi]]);
        float zz = z[r] + badd * outW[128] + outB[0];
        out[pi] = 1.f / (1.f + __expf(-zz));
      }
    }
  }
}

extern "C" void kernel_launch(void* const* d_in, const int* in_sizes, int n_in,
                              void* d_out, int out_size, void* d_ws, size_t ws_size,
                              hipStream_t stream) {
  (void)in_sizes; (void)n_in; (void)out_size; (void)ws_size;
  const int* aidx = (const int*)d_in[0];
  const int* bidx = (const int*)d_in[1];
  const int* adj = (const int*)d_in[2];
  const float* emb = (const float*)d_in[3];
  const float* embB = (const float*)d_in[4];
  const float* W1 = (const float*)d_in[5];
  const float* av1 = (const float*)d_in[6];
  const float* W2 = (const float*)d_in[7];
  const float* av2 = (const float*)d_in[8];
  const float* amix = (const float*)d_in[9];
  const float* bmix = (const float*)d_in[10];
  const float* linW = (const float*)d_in[11];
  const float* linB = (const float*)d_in[12];
  const float* outW = (const float*)d_in[13];
  const float* outB = (const float*)d_in[14];

  char* ws = (char*)d_ws;
  u64* bm = (u64*)(ws + 0);                           // 2MB
  u16* WhTF = (u16*)(ws + (2u << 20));                // 3MB fragment-major
  float* E1 = (float*)(ws + (5u << 20));              // 48KB each
  float* F1 = (float*)(ws + (5u << 20) + (64u << 10));
  float* E2 = (float*)(ws + (5u << 20) + (128u << 10));
  float* F2 = (float*)(ws + (5u << 20) + (192u << 10));
  u16* linWT = (u16*)(ws + (5u << 20) + (256u << 10));  // 96KB
  u16* WT1 = (u16*)(ws + (5u << 20) + (384u << 10));    // 192KB
  u16* WT2 = (u16*)(ws + (5u << 20) + (640u << 10));    // 288KB
  float* at1f = (float*)(ws + (6u << 20));            // 6MB
  u16* sh12 = (u16*)(ws + (12u << 20));               // 3MB: emb16 -> at1b/attB
  u16* emb16 = sh12;
  u16* at1b = sh12;
  u16* attB = sh12;
  unsigned int* bmF = (unsigned int*)(ws + (15u << 20));  // 2MB

  k_bitmask<<<NN, 256, 0, stream>>>(adj, bm);
  k_maskf<<<2048, 256, 0, stream>>>(bm, bmF);
  k_prep<<<5248, 256, 0, stream>>>(emb, W1, W2, linW, emb16, WT1, WT2, linWT);
  k_wh<256><<<dim3(256, NH), 64, 0, stream>>>(emb16, WT1, av1, WhTF, E1, F1, E2, F2);
  k_acc<<<dim3(64, NH), 512, 0, stream>>>(bmF, WhTF, E1, F1, E2, F2, at1f,
                                          amix, bmix, at1f, at1b, attB, 0);
  k_wh<384><<<dim3(256, NH), 64, 0, stream>>>(at1b, WT2, av2, WhTF, E1, F1, E2, F2);
  k_acc<<<dim3(64, NH), 512, 0, stream>>>(bmF, WhTF, E1, F1, E2, F2, at1f,
                                          amix, bmix, at1f, at1b, attB, 1);
  k_pairs<<<NPAIR / 256, 512, 0, stream>>>(aidx, bidx, attB, linWT, linB, outW,
                                           outB, embB, (float*)d_out);
}